// Round 1
// baseline (89.354 us; speedup 1.0000x reference)
//
#include <hip/hip_runtime.h>

#define FEPS 1e-5f

constexpr int Bn = 4, Hn = 16, Sn = 4096, Dn = 64;
constexpr int NHEAD = Bn * Hn;          // 64 heads
constexpr int CHUNKS = 16;              // pass1 S-chunks per head
constexpr int CH_S = Sn / CHUNKS;       // 256 rows per pass1 block
constexpr int SUB = 32;                 // rows staged in LDS at a time
constexpr int SLOT = Dn * Dn + Dn;      // 4160 floats: kv then ksum

// ---------------- Pass 1: partial kv = K^T V and k_sum over an S-chunk ----------------
template <bool PART>
__global__ __launch_bounds__(256) void pass1(const float* __restrict__ K,
                                             const float* __restrict__ V,
                                             float* __restrict__ ksum,
                                             float* __restrict__ kv,
                                             float* __restrict__ part) {
    const int head = blockIdx.x;
    const int chunk = blockIdx.y;
    const int t = threadIdx.x;
    const int ti = t >> 4, tj = t & 15;
    const int d0 = ti * 4, e0 = tj * 4;   // this thread's 4x4 kv tile

    const float4* Ksrc = (const float4*)(K + ((size_t)head * Sn + (size_t)chunk * CH_S) * Dn);
    const float4* Vsrc = (const float4*)(V + ((size_t)head * Sn + (size_t)chunk * CH_S) * Dn);

    __shared__ float kbuf[SUB][68];   // +4 pad: bank rotation, keeps 16B alignment
    __shared__ float vbuf[SUB][68];

    float acc[4][4] = {};
    float ksx = 0.f, ksy = 0.f, ksz = 0.f, ksw = 0.f;  // k_sum partial for dims 4*(t&15)..+3

    const int s0 = t >> 4;          // 0..15
    const int dd = (t & 15) * 4;    // 0..60

    for (int sc = 0; sc < CH_S / SUB; ++sc) {
        float4 k0 = Ksrc[sc * 512 + t];
        float4 k1 = Ksrc[sc * 512 + t + 256];
        float4 v0 = Vsrc[sc * 512 + t];
        float4 v1 = Vsrc[sc * 512 + t + 256];
        __syncthreads();  // previous sub-chunk compute done before overwrite
        *(float4*)&kbuf[s0][dd] = k0;
        *(float4*)&kbuf[s0 + 16][dd] = k1;
        *(float4*)&vbuf[s0][dd] = v0;
        *(float4*)&vbuf[s0 + 16][dd] = v1;
        ksx += k0.x + k1.x; ksy += k0.y + k1.y;
        ksz += k0.z + k1.z; ksw += k0.w + k1.w;
        __syncthreads();
        #pragma unroll 8
        for (int s = 0; s < SUB; ++s) {
            float4 a = *(const float4*)&kbuf[s][d0];
            float4 b = *(const float4*)&vbuf[s][e0];
            float av[4] = {a.x, a.y, a.z, a.w};
            float bv[4] = {b.x, b.y, b.z, b.w};
            #pragma unroll
            for (int i = 0; i < 4; ++i)
                #pragma unroll
                for (int j = 0; j < 4; ++j) acc[i][j] += av[i] * bv[j];
        }
    }

    // commit kv partial
    float* slot = PART ? (part + ((size_t)chunk * NHEAD + head) * SLOT) : nullptr;
    if (PART) {
        #pragma unroll
        for (int i = 0; i < 4; ++i) {
            float4 r;
            r.x = acc[i][0]; r.y = acc[i][1]; r.z = acc[i][2]; r.w = acc[i][3];
            *(float4*)&slot[(d0 + i) * Dn + e0] = r;
        }
    } else {
        float* kvh = kv + (size_t)head * Dn * Dn;
        #pragma unroll
        for (int i = 0; i < 4; ++i)
            #pragma unroll
            for (int j = 0; j < 4; ++j) atomicAdd(&kvh[(d0 + i) * Dn + e0 + j], acc[i][j]);
    }

    // k_sum: reduce the 16 threads sharing each d4 group via LDS
    __syncthreads();
    float* red = &kbuf[0][0];  // 1024 floats needed, kbuf has 2176
    {
        float4 r; r.x = ksx; r.y = ksy; r.z = ksz; r.w = ksw;
        *(float4*)&red[t * 4] = r;
    }
    __syncthreads();
    if (t < 16) {
        float4 tot = {0.f, 0.f, 0.f, 0.f};
        #pragma unroll
        for (int g = 0; g < 16; ++g) {
            float4 v = *(const float4*)&red[(t + 16 * g) * 4];
            tot.x += v.x; tot.y += v.y; tot.z += v.z; tot.w += v.w;
        }
        if (PART) {
            *(float4*)&slot[Dn * Dn + t * 4] = tot;
        } else {
            atomicAdd(&ksum[head * Dn + t * 4 + 0], tot.x);
            atomicAdd(&ksum[head * Dn + t * 4 + 1], tot.y);
            atomicAdd(&ksum[head * Dn + t * 4 + 2], tot.z);
            atomicAdd(&ksum[head * Dn + t * 4 + 3], tot.w);
        }
    }
}

// ---------------- Reduce 16 chunk-partials -> final ksum/kv ----------------
__global__ __launch_bounds__(256) void reduce_partials(const float* __restrict__ part,
                                                       float* __restrict__ ksum,
                                                       float* __restrict__ kv) {
    const int head = blockIdx.x;
    const int idx = blockIdx.y * 256 + threadIdx.x;
    if (idx >= SLOT) return;
    float s = 0.f;
    #pragma unroll
    for (int c = 0; c < CHUNKS; ++c)
        s += part[((size_t)c * NHEAD + head) * SLOT + idx];
    if (idx < Dn * Dn)
        kv[(size_t)head * Dn * Dn + idx] = s;
    else
        ksum[head * Dn + (idx - Dn * Dn)] = s;
}

// ---------------- Pass 2: out = (Q / (Q.ksum + eps)) @ kv ----------------
__global__ __launch_bounds__(256) void pass2(const float* __restrict__ Q,
                                             const float* __restrict__ ksum,
                                             const float* __restrict__ kv,
                                             float* __restrict__ out) {
    const int head = blockIdx.x;
    const int rc = blockIdx.y;  // 64-row chunk
    const int t = threadIdx.x;
    const int ti = t >> 4, tj = t & 15;
    const int r0 = ti * 4, e0 = tj * 4;   // 4 rows x 4 cols per thread

    __shared__ float kvs[Dn][Dn];
    __shared__ float qT[Dn][68];          // transposed Q tile, padded
    __shared__ float kss[Dn];

    // stage kv (16KB; L2-resident after reduce)
    const float4* kvsrc = (const float4*)(kv + (size_t)head * Dn * Dn);
    float4* kvdst = (float4*)&kvs[0][0];
    #pragma unroll
    for (int kk = 0; kk < 4; ++kk) kvdst[t + 256 * kk] = kvsrc[t + 256 * kk];
    if (t < 16) ((float4*)kss)[t] = ((const float4*)(ksum + head * Dn))[t];

    // stage Q tile transposed: qT[d][row]
    const float4* Qsrc = (const float4*)(Q + ((size_t)head * Sn + (size_t)rc * 64) * Dn);
    #pragma unroll
    for (int kk = 0; kk < 4; ++kk) {
        int f = t + 256 * kk;
        int row = f >> 4, d4 = (f & 15) * 4;
        float4 q4 = Qsrc[f];
        qT[d4 + 0][row] = q4.x;
        qT[d4 + 1][row] = q4.y;
        qT[d4 + 2][row] = q4.z;
        qT[d4 + 3][row] = q4.w;
    }
    __syncthreads();

    float acc[4][4] = {};
    float dn[4] = {0.f, 0.f, 0.f, 0.f};
    #pragma unroll 8
    for (int d = 0; d < Dn; ++d) {
        float4 a = *(const float4*)&qT[d][r0];     // q for 4 rows at dim d
        float4 b = *(const float4*)&kvs[d][e0];    // kv row d, 4 cols
        float ks = kss[d];
        float av[4] = {a.x, a.y, a.z, a.w};
        float bv[4] = {b.x, b.y, b.z, b.w};
        #pragma unroll
        for (int i = 0; i < 4; ++i) {
            dn[i] += av[i] * ks;
            #pragma unroll
            for (int j = 0; j < 4; ++j) acc[i][j] += av[i] * bv[j];
        }
    }

    float* Oh = out + ((size_t)head * Sn + (size_t)rc * 64) * Dn;
    #pragma unroll
    for (int i = 0; i < 4; ++i) {
        float inv = 1.0f / (dn[i] + FEPS);
        float4 r;
        r.x = acc[i][0] * inv; r.y = acc[i][1] * inv;
        r.z = acc[i][2] * inv; r.w = acc[i][3] * inv;
        *(float4*)&Oh[(size_t)(r0 + i) * Dn + e0] = r;
    }
}

extern "C" void kernel_launch(void* const* d_in, const int* in_sizes, int n_in,
                              void* d_out, int out_size, void* d_ws, size_t ws_size,
                              hipStream_t stream) {
    (void)in_sizes; (void)n_in; (void)out_size;
    const float* Q = (const float*)d_in[0];
    const float* K = (const float*)d_in[1];
    const float* V = (const float*)d_in[2];
    float* out = (float*)d_out;

    float* ksum = (float*)d_ws;                          // [64][64]
    float* kv = ksum + (size_t)NHEAD * Dn;               // [64][64*64]
    const size_t final_bytes = (size_t)NHEAD * SLOT * sizeof(float);          // ~1.02 MB
    const size_t part_bytes = (size_t)CHUNKS * NHEAD * SLOT * sizeof(float);  // ~17 MB

    if (ws_size >= final_bytes + part_bytes) {
        float* part = kv + (size_t)NHEAD * Dn * Dn;
        hipLaunchKernelGGL((pass1<true>), dim3(NHEAD, CHUNKS), dim3(256), 0, stream,
                           K, V, ksum, kv, part);
        hipLaunchKernelGGL(reduce_partials, dim3(NHEAD, (SLOT + 255) / 256), dim3(256), 0, stream,
                           part, ksum, kv);
    } else {
        hipMemsetAsync(d_ws, 0, final_bytes, stream);
        hipLaunchKernelGGL((pass1<false>), dim3(NHEAD, CHUNKS), dim3(256), 0, stream,
                           K, V, ksum, kv, (float*)nullptr);
    }
    hipLaunchKernelGGL(pass2, dim3(NHEAD, Sn / 64), dim3(256), 0, stream,
                       Q, ksum, kv, out);
}